// Round 4
// baseline (508.053 us; speedup 1.0000x reference)
//
#include <hip/hip_runtime.h>
#include <hip/hip_bf16.h>

// Problem constants
#define Bsz 128
#define Ssz 256
#define Lsz 200
#define Dsz 768
#define POS_DIM 50
#define TAGS 5
#define NROW 25600          // B*L
#define FIN 818             // D + POS_DIM
#define KH 832              // FIN padded to mult of 32
#define KR 416              // REDUC=400 padded
#define KD 160              // HID=150 padded

typedef __attribute__((ext_vector_type(8))) short short8;
typedef __attribute__((ext_vector_type(4))) short short4v;
typedef __attribute__((ext_vector_type(4))) float floatx4;

__device__ __forceinline__ short f2bf(float v) {
    __hip_bfloat16 h = __float2bfloat16(v);
    short s; __builtin_memcpy(&s, &h, 2); return s;
}
__device__ __forceinline__ float bf2f(short s) {
    __hip_bfloat16 h; __builtin_memcpy(&h, &s, 2);
    return __bfloat162float(h);
}

// ---------------------------------------------------------------------------
// prep: zero-padded bf16 weights + padded fp32 biases.
// Feature permutation for the reduc GEMM: k=0..767 <- bert dims,
// k=768..817 <- pos-emb dims, k=818..831 zero. Wr_bf permuted to match.
//   Wr_bf  [512][832], Wh_bf [640][416], Wbi_bf [640][160]
//   br_pad[416], bh_pad[640], bbi_pad[640] (= W_bi[:,150])
// ---------------------------------------------------------------------------
__global__ void prep_kernel(const float* __restrict__ W_reduc,
                            const float* __restrict__ W_ap, const float* __restrict__ W_op,
                            const float* __restrict__ W_ap2, const float* __restrict__ W_op2,
                            const float* __restrict__ W_bi,
                            const float* __restrict__ b_reduc,
                            const float* __restrict__ b_ap, const float* __restrict__ b_op,
                            const float* __restrict__ b_ap2, const float* __restrict__ b_op2,
                            short* __restrict__ Wr_bf, short* __restrict__ Wh_bf,
                            short* __restrict__ Wbi_bf,
                            float* __restrict__ br_pad, float* __restrict__ bh_pad,
                            float* __restrict__ bbi_pad)
{
    int i = blockIdx.x * blockDim.x + threadIdx.x;
    if (i < 512 * KH) {
        int r = i / KH, k = i % KH;
        float v = 0.0f;
        if (r < 400) {
            if (k < 768)       v = W_reduc[r * FIN + POS_DIM + k];   // bert dim k
            else if (k < 818)  v = W_reduc[r * FIN + (k - 768)];     // pos dim
        }
        Wr_bf[i] = f2bf(v);
    }
    if (i < 640 * KR) {
        int r = i / KR, c = i % KR;
        float v = 0.0f;
        if (r < 600 && c < 400) {
            const float* src = (r < 150) ? W_ap : (r < 300) ? W_op : (r < 450) ? W_ap2 : W_op2;
            v = src[(r % 150) * 400 + c];
        }
        Wh_bf[i] = f2bf(v);
    }
    if (i < 640 * KD) {
        int r = i / KD, c = i % KD;
        Wbi_bf[i] = (r < 600 && c < 150) ? f2bf(W_bi[r * 151 + c]) : (short)0;
    }
    if (i < KR) br_pad[i] = (i < 400) ? b_reduc[i] : 0.0f;
    if (i < 640) {
        float v = 0.0f;
        if (i < 600) {
            const float* bs = (i < 150) ? b_ap : (i < 300) ? b_op : (i < 450) ? b_ap2 : b_op2;
            v = bs[i % 150];
        }
        bh_pad[i] = v;
        bbi_pad[i] = (i < 600) ? W_bi[i * 151 + 150] : 0.0f;
    }
}

// ---------------------------------------------------------------------------
// pool (permuted layout): h_bf[row][0:768]=span-mean bert (float4 reads),
// [768:818]=embed[tag], [818:832]=0. One row per block, short4 writes.
// ---------------------------------------------------------------------------
__global__ __launch_bounds__(256) void pool_kernel(
    const float* __restrict__ bert,
    const int* __restrict__ positions,
    const int* __restrict__ postag,
    const float* __restrict__ embed,
    short* __restrict__ h_bf)
{
    int row = blockIdx.x;
    int b = row / Lsz;
    int st = positions[row * 2 + 0];
    int en = positions[row * 2 + 1];
    int tag = postag[row];
    int span = en - st + 1;
    float inv = 1.0f / (float)span;
    const float* base = bert + ((long)b * Ssz + st) * Dsz;
    short* hr = h_bf + (long)row * KH;

    int t = threadIdx.x;
    int c0 = t * 4;                    // 4 columns per thread; 256*4=1024 >= 832
    if (c0 >= KH) return;
    short4v o;
    if (c0 < 768) {
        float4 s = {0.f, 0.f, 0.f, 0.f};
        for (int i = 0; i < span; ++i) {
            float4 v = *(const float4*)(base + i * Dsz + c0);
            s.x += v.x; s.y += v.y; s.z += v.z; s.w += v.w;
        }
        o.x = f2bf(s.x * inv); o.y = f2bf(s.y * inv);
        o.z = f2bf(s.z * inv); o.w = f2bf(s.w * inv);
    } else {
        const float* e = embed + tag * POS_DIM;
#pragma unroll
        for (int j = 0; j < 4; ++j) {
            int c = c0 + j - 768;      // embed idx
            float v = (c < POS_DIM) ? e[c] : 0.0f;
            ((short*)&o)[j] = f2bf(v);
        }
    }
    *(short4v*)(hr + c0) = o;
}

// ---------------------------------------------------------------------------
// MFMA bf16 GEMM, direct-to-register (no LDS, no barriers):
// C[m,n] = sum_k A[m,k]*Bt[n,k]. Block tile 64(M)x128(N), 4 waves; wave wv
// owns 64 rows x cols [wv*32, wv*32+32) -> 4x2 mfma 16x16x32 tiles.
// Fragment loads are per-lane global_load_dwordx4:
//   A-frag(mt): lane -> A[row0 + mt*16 + lm][k0 + lk*8 .. +8]
//   B-frag(nt): lane -> Bt[col0 + wv*32 + nt*16 + lm][k0 + lk*8 .. +8]
// (16 rows x 64B contiguous per instruction; A tile 4KB/iter is L1-hot,
//  B weights are L2-hot across hundreds of blocks.)
// Software pipeline: prefetch iter i+1's 6 fragments while MFMA'ing iter i.
// K mult of 32; loads unguarded (padded weight arrays; A overrun lands in
// adjacent ws data, discarded by epilogue guards).
// Epilogue modes:
//  0: outB[m*ldc+n] = bf(acc+bias[n]), n<Nv
//  1: hidden: n<600 -> hid4[(n/150)*NROW+m][n%150] = bf(relu(acc+bias[n]));
//     n in [600,640) -> zero pad cols
//  2: affine: n<600 -> aff[((m/200)*800+(m%200)*4+n/150)*160+n%150]
//     = bf(acc+bias[n]); n in [600,640) -> zero pads
//  3: outF[bz*sCb + m*ldc+n] = acc  (m<M, n<Nv)
// ---------------------------------------------------------------------------
__global__ __launch_bounds__(256, 4) void gemm_mfma(
    const short* __restrict__ A, long long sAb, int lda,
    const short* __restrict__ Bt, long long sBb, int ldb,
    const float* __restrict__ bias,
    short* __restrict__ outB, float* __restrict__ outF, long long sCb, int ldc,
    int M, int Nv, int K, int mode)
{
    int bz = blockIdx.z;
    A += (long long)bz * sAb;
    Bt += (long long)bz * sBb;

    int row0 = blockIdx.y * 64;
    int col0 = blockIdx.x * 128;
    int lane = threadIdx.x & 63;
    int wv = threadIdx.x >> 6;
    int lm = lane & 15, lk = lane >> 4;

    // per-lane fragment base pointers (k0 added per iteration)
    const short* pA = A + (long)(row0 + lm) * lda + lk * 8;
    const short* pB = Bt + (long)(col0 + wv * 32 + lm) * ldb + lk * 8;
    long ldA16 = (long)lda * 16, ldB16 = (long)ldb * 16;

    floatx4 acc[4][2];
#pragma unroll
    for (int i = 0; i < 4; ++i)
#pragma unroll
        for (int j = 0; j < 2; ++j)
            acc[i][j] = (floatx4){0.f, 0.f, 0.f, 0.f};

    short8 a0[4], b0[2], a1[4], b1[2];

#define LOADF(k0, aa, bb)                                              \
    {                                                                  \
        _Pragma("unroll")                                              \
        for (int mt = 0; mt < 4; ++mt)                                 \
            aa[mt] = *(const short8*)(pA + mt * ldA16 + (k0));         \
        _Pragma("unroll")                                              \
        for (int nt = 0; nt < 2; ++nt)                                 \
            bb[nt] = *(const short8*)(pB + nt * ldB16 + (k0));         \
    }
#define MFMAF(aa, bb)                                                  \
    {                                                                  \
        _Pragma("unroll")                                              \
        for (int mt = 0; mt < 4; ++mt)                                 \
            _Pragma("unroll")                                          \
            for (int nt = 0; nt < 2; ++nt)                             \
                acc[mt][nt] = __builtin_amdgcn_mfma_f32_16x16x32_bf16( \
                    aa[mt], bb[nt], acc[mt][nt], 0, 0, 0);             \
    }

    int niter = K >> 5;               // K mult of 32
    LOADF(0, a0, b0);
    for (int i = 0; i + 1 < niter; i += 2) {
        LOADF((i + 1) * 32, a1, b1);
        MFMAF(a0, b0);
        if (i + 2 < niter) LOADF((i + 2) * 32, a0, b0);
        MFMAF(a1, b1);
    }
    if (niter & 1) MFMAF(a0, b0);

    // epilogue
#pragma unroll
    for (int mt = 0; mt < 4; ++mt) {
#pragma unroll
        for (int nt = 0; nt < 2; ++nt) {
#pragma unroll
            for (int r = 0; r < 4; ++r) {
                int gm = row0 + mt * 16 + lk * 4 + r;
                int gn = col0 + wv * 32 + nt * 16 + lm;
                float v = acc[mt][nt][r];
                if (mode == 0) {
                    if (gn < Nv)
                        outB[(long)gm * ldc + gn] = f2bf(v + bias[gn]);
                } else if (mode == 1) {
                    if (gn < 600) {
                        v = fmaxf(v + bias[gn], 0.0f);
                        outB[((long)(gn / 150) * NROW + gm) * KD + gn % 150] = f2bf(v);
                    } else if (gn < 640) {
                        int q = gn - 600;
                        outB[((long)(q / 10) * NROW + gm) * KD + 150 + q % 10] = 0;
                    }
                } else if (mode == 2) {
                    int bb = gm / 200, l = gm % 200;
                    if (gn < 600) {
                        v += bias[gn];
                        outB[((long)bb * 800 + l * 4 + gn / 150) * KD + gn % 150] = f2bf(v);
                    } else if (gn < 640) {
                        int q = gn - 600;
                        outB[((long)bb * 800 + l * 4 + q / 10) * KD + 150 + q % 10] = 0;
                    }
                } else {
                    if (gm < M && gn < Nv)
                        outF[(long long)bz * sCb + (long)gm * ldc + gn] = v;
                }
            }
        }
    }
#undef LOADF
#undef MFMAF
}

// ---------------------------------------------------------------------------
// tags: per-row K=150 dots from bf16 ap_rep/op_rep (hid4[0], hid4[1])
// ---------------------------------------------------------------------------
__global__ __launch_bounds__(256) void tags_kernel(
    const short* __restrict__ hid4,
    const float* __restrict__ W_aptag, const float* __restrict__ b_aptag,
    const float* __restrict__ W_optag, const float* __restrict__ b_optag,
    float* __restrict__ out_ap, float* __restrict__ out_op)
{
    int wave = threadIdx.x / 64;
    int lane = threadIdx.x % 64;
    int row = blockIdx.x * 4 + wave;
    if (row >= NROW) return;

#pragma unroll
    for (int which = 0; which < 2; ++which) {
        const short* rep = hid4 + ((long)which * NROW + row) * KD;
        const float* W = which ? W_optag : W_aptag;
        const float* bb = which ? b_optag : b_aptag;
        float* out = which ? out_op : out_ap;
        float v0 = bf2f(rep[lane]);
        float v1 = bf2f(rep[64 + lane]);
        float v2 = (lane < 22) ? bf2f(rep[128 + lane]) : 0.0f;
#pragma unroll
        for (int t = 0; t < TAGS; ++t) {
            const float* w = W + t * 150;
            float p = v0 * w[lane] + v1 * w[64 + lane] +
                      ((lane < 22) ? v2 * w[128 + lane] : 0.0f);
#pragma unroll
            for (int off = 32; off > 0; off >>= 1) p += __shfl_down(p, off);
            if (lane == 0) out[row * TAGS + t] = p + bb[t];
        }
    }
}

// ---------------------------------------------------------------------------
extern "C" void kernel_launch(void* const* d_in, const int* in_sizes, int n_in,
                              void* d_out, int out_size, void* d_ws, size_t ws_size,
                              hipStream_t stream)
{
    const float* bert      = (const float*)d_in[0];
    const int*   positions = (const int*)d_in[1];
    const int*   postag    = (const int*)d_in[2];
    const float* embed     = (const float*)d_in[3];
    const float* W_reduc   = (const float*)d_in[4];
    const float* b_reduc   = (const float*)d_in[5];
    const float* W_ap      = (const float*)d_in[6];
    const float* b_ap      = (const float*)d_in[7];
    const float* W_op      = (const float*)d_in[8];
    const float* b_op      = (const float*)d_in[9];
    const float* W_ap2     = (const float*)d_in[10];
    const float* b_ap2     = (const float*)d_in[11];
    const float* W_op2     = (const float*)d_in[12];
    const float* b_op2     = (const float*)d_in[13];
    const float* W_aptag   = (const float*)d_in[14];
    const float* b_aptag   = (const float*)d_in[15];
    const float* W_optag   = (const float*)d_in[16];
    const float* b_optag   = (const float*)d_in[17];
    const float* W_bi      = (const float*)d_in[18];

    float* out = (float*)d_out;
    float* out_ap  = out;                       // [25600,5]
    float* out_op  = out + NROW * TAGS;         // [25600,5]
    float* out_tri = out + 2 * NROW * TAGS;     // [128,200,800]

    // workspace layout (shorts)
    short* ws = (short*)d_ws;
    short* h_bf     = ws;                               // 25600*832 = 21,299,200
    short* affine   = h_bf;                             // alias (h dead after GEMM1)
    short* reduc_bf = h_bf + (long)NROW * KH;           // 25600*416
    short* hid4     = reduc_bf + (long)NROW * KR;       // 4*25600*160
    short* Wr_bf    = hid4 + (long)4 * NROW * KD;       // 512*832
    short* Wh_bf    = Wr_bf + 512 * KH;                 // 640*416
    short* Wbi_bf   = Wh_bf + 640 * KR;                 // 640*160
    float* br_pad   = (float*)(Wbi_bf + 640 * KD);      // 416
    float* bh_pad   = br_pad + KR;                      // 640
    float* bbi_pad  = bh_pad + 640;                     // 640

    // 1. weight prep
    prep_kernel<<<(512 * KH + 255) / 256, 256, 0, stream>>>(
        W_reduc, W_ap, W_op, W_ap2, W_op2, W_bi,
        b_reduc, b_ap, b_op, b_ap2, b_op2,
        Wr_bf, Wh_bf, Wbi_bf, br_pad, bh_pad, bbi_pad);

    // 2. pool -> h_bf [25600][832] (bert-first permuted layout)
    pool_kernel<<<NROW, 256, 0, stream>>>(bert, positions, postag, embed, h_bf);

    // 3. reduc_bf = bf(h @ Wr^T + br)  M=25600 N=416 K=832; grid 4x400
    {
        dim3 g(4, NROW / 64, 1);
        gemm_mfma<<<g, 256, 0, stream>>>(h_bf, 0, KH, Wr_bf, 0, KH, br_pad,
                                         reduc_bf, nullptr, 0, KR,
                                         NROW, KR, KH, 0);
    }
    // 4. hid4 = relu(reduc @ Wh^T + bh); grid 5x400
    {
        dim3 g(5, NROW / 64, 1);
        gemm_mfma<<<g, 256, 0, stream>>>(reduc_bf, 0, KR, Wh_bf, 0, KR, bh_pad,
                                         hid4, nullptr, 0, 0,
                                         NROW, 600, KR, 1);
    }
    // 5. tag heads
    tags_kernel<<<NROW / 4, 256, 0, stream>>>(hid4, W_aptag, b_aptag,
                                              W_optag, b_optag, out_ap, out_op);
    // 6. affine = ap_node @ Wbi^T + bbi -> scattered [128][800][160] bf16
    {
        dim3 g(5, NROW / 64, 1);
        gemm_mfma<<<g, 256, 0, stream>>>(hid4 + (long)2 * NROW * KD, 0, KD,
                                         Wbi_bf, 0, KD, bbi_pad,
                                         affine, nullptr, 0, 0,
                                         NROW, 600, KD, 2);
    }
    // 7. tri: per batch, C[l2][k] = op_node[l2,:]·affine[k,:]; grid 7x4x128
    {
        dim3 g(7, 4, Bsz);
        gemm_mfma<<<g, 256, 0, stream>>>(hid4 + (long)3 * NROW * KD, (long long)200 * KD, KD,
                                         affine, (long long)800 * KD, KD, nullptr,
                                         nullptr, out_tri, (long long)200 * 800, 800,
                                         200, 800, KD, 3);
    }
}